// Round 1
// baseline (1401.245 us; speedup 1.0000x reference)
//
#include <hip/hip_runtime.h>
#include <cmath>

#define CCH 16                 // channels per chunk
#define DD  4096               // D1 == D2
#define HSZ (DD * CCH)         // 65536
#define HSZ4 (HSZ / 4)         // 16384 float4 per row of W1

struct DanW {
    const float *Wd1, *bd1, *Wd2, *bd2, *Wd3, *bd3;
};

__device__ __forceinline__ float leaky(float v) {
    return v > 0.0f ? v : 0.01f * v;
}

// z = [h[0..15], onehot(code)] -> Linear(19,15) lrelu -> Linear(15,8) lrelu -> Linear(8,1) -> tanh
__device__ __forceinline__ float dan_tanh(const float* h, int code, DanW d) {
    float t[15];
#pragma unroll
    for (int o = 0; o < 15; ++o) {
        float acc = d.bd1[o] + d.Wd1[(CCH + code) * 15 + o];  // one-hot contribution
#pragma unroll
        for (int i = 0; i < CCH; ++i) acc = fmaf(h[i], d.Wd1[i * 15 + o], acc);
        t[o] = leaky(acc);
    }
    float u[8];
#pragma unroll
    for (int o = 0; o < 8; ++o) {
        float acc = d.bd2[o];
#pragma unroll
        for (int i = 0; i < 15; ++i) acc = fmaf(t[i], d.Wd2[i * 8 + o], acc);
        u[o] = leaky(acc);
    }
    float v = d.bd3[0];
#pragma unroll
    for (int i = 0; i < 8; ++i) v = fmaf(u[i], d.Wd3[i], v);
    return tanhf(v);
}

// Kernel 1: h0 = x*W0 + b0 (per 16-chunk), DAN code 0 -> a0[4096]
__global__ __launch_bounds__(64) void k_layer0(const float* __restrict__ x,
                                               const float* __restrict__ W0,
                                               const float* __restrict__ b0,
                                               float* __restrict__ a0, DanW d) {
    int j = blockIdx.x * 64 + threadIdx.x;  // chunk index 0..4095
    if (j >= DD) return;
    float xv = x[0];
    const float4* w4 = (const float4*)W0 + j * 4;
    const float4* b4 = (const float4*)b0 + j * 4;
    float h[CCH];
#pragma unroll
    for (int q = 0; q < 4; ++q) {
        float4 w = w4[q], b = b4[q];
        h[q * 4 + 0] = fmaf(xv, w.x, b.x);
        h[q * 4 + 1] = fmaf(xv, w.y, b.y);
        h[q * 4 + 2] = fmaf(xv, w.z, b.z);
        h[q * 4 + 3] = fmaf(xv, w.w, b.w);
    }
    a0[j] = dan_tanh(h, 0, d);
}

// Kernel 2: the 1 GiB streamer. partial[ry][k] = sum_{i in row-chunk ry} a0[i] * W1[i, k]
__global__ __launch_bounds__(256) void k_gemv(const float* __restrict__ a0,
                                              const float* __restrict__ W1,
                                              float* __restrict__ partial, int rps) {
    __shared__ float s[DD];  // only first rps used (<= 16 KiB)
    int tid = threadIdx.x;
    int row0 = blockIdx.y * rps;
    for (int i = tid; i < rps; i += 256) s[i] = a0[row0 + i];
    __syncthreads();

    int k4 = blockIdx.x * 256 + tid;  // float4 column index, 0..16383
    const float4* p = (const float4*)W1 + (size_t)row0 * HSZ4 + k4;
    float4 acc = make_float4(0.f, 0.f, 0.f, 0.f);
#pragma unroll 8
    for (int i = 0; i < rps; ++i) {
        float4 w = p[(size_t)i * HSZ4];
        float a = s[i];
        acc.x = fmaf(a, w.x, acc.x);
        acc.y = fmaf(a, w.y, acc.y);
        acc.z = fmaf(a, w.z, acc.z);
        acc.w = fmaf(a, w.w, acc.w);
    }
    ((float4*)partial)[(size_t)blockIdx.y * HSZ4 + k4] = acc;
}

// Kernel 3: h1 = sum partials + b1 + x*Ws02 + bs02, DAN code 1 -> a1[4096]
__global__ __launch_bounds__(64) void k_danlayer1(const float* __restrict__ partial, int rsplit,
                                                  const float* __restrict__ b1,
                                                  const float* __restrict__ Ws02,
                                                  const float* __restrict__ bs02,
                                                  const float* __restrict__ x,
                                                  float* __restrict__ a1, DanW d) {
    int j = blockIdx.x * 64 + threadIdx.x;
    if (j >= DD) return;
    float xv = x[0];
    float h[CCH];
#pragma unroll
    for (int q = 0; q < 4; ++q) {
        float4 bb = ((const float4*)b1)[j * 4 + q];
        float4 w2 = ((const float4*)Ws02)[j * 4 + q];
        float4 bs = ((const float4*)bs02)[j * 4 + q];
        h[q * 4 + 0] = bb.x + fmaf(xv, w2.x, bs.x);
        h[q * 4 + 1] = bb.y + fmaf(xv, w2.y, bs.y);
        h[q * 4 + 2] = bb.z + fmaf(xv, w2.z, bs.z);
        h[q * 4 + 3] = bb.w + fmaf(xv, w2.w, bs.w);
    }
    for (int sgl = 0; sgl < rsplit; ++sgl) {
#pragma unroll
        for (int q = 0; q < 4; ++q) {
            float4 pv = ((const float4*)partial)[(size_t)sgl * HSZ4 + j * 4 + q];
            h[q * 4 + 0] += pv.x;
            h[q * 4 + 1] += pv.y;
            h[q * 4 + 2] += pv.z;
            h[q * 4 + 3] += pv.w;
        }
    }
    a1[j] = dan_tanh(h, 1, d);
}

// Kernel 4: h2 = a1@W2 + b2 + a0@Ws13 + bs13 (16 cols), DAN code 2 -> out[0]
__global__ __launch_bounds__(256) void k_final(const float* __restrict__ a0,
                                               const float* __restrict__ a1,
                                               const float* __restrict__ W2,
                                               const float* __restrict__ b2,
                                               const float* __restrict__ Ws13,
                                               const float* __restrict__ bs13,
                                               float* __restrict__ out, DanW d) {
    __shared__ float red[CCH * 256];  // [c][tid]
    __shared__ float h2s[CCH];
    int tid = threadIdx.x;
    float acc[CCH];
#pragma unroll
    for (int c = 0; c < CCH; ++c) acc[c] = 0.f;
    for (int i = tid; i < DD; i += 256) {
        float av = a1[i], a0v = a0[i];
        const float4* w2 = (const float4*)W2 + i * 4;
        const float4* ws = (const float4*)Ws13 + i * 4;
#pragma unroll
        for (int q = 0; q < 4; ++q) {
            float4 w = w2[q], sv = ws[q];
            acc[q * 4 + 0] += fmaf(av, w.x, a0v * sv.x);
            acc[q * 4 + 1] += fmaf(av, w.y, a0v * sv.y);
            acc[q * 4 + 2] += fmaf(av, w.z, a0v * sv.z);
            acc[q * 4 + 3] += fmaf(av, w.w, a0v * sv.w);
        }
    }
#pragma unroll
    for (int c = 0; c < CCH; ++c) red[c * 256 + tid] = acc[c];
    __syncthreads();
    if (tid < CCH) {
        float s = 0.f;
        for (int i = 0; i < 256; ++i) s += red[tid * 256 + i];
        h2s[tid] = s + b2[tid] + bs13[tid];
    }
    __syncthreads();
    if (tid == 0) {
        float h[CCH];
#pragma unroll
        for (int c = 0; c < CCH; ++c) h[c] = h2s[c];
        out[0] = dan_tanh(h, 2, d);
    }
}

extern "C" void kernel_launch(void* const* d_in, const int* in_sizes, int n_in,
                              void* d_out, int out_size, void* d_ws, size_t ws_size,
                              hipStream_t stream) {
    const float* x    = (const float*)d_in[0];
    const float* W0   = (const float*)d_in[1];
    const float* b0   = (const float*)d_in[2];
    const float* W1   = (const float*)d_in[3];
    const float* b1   = (const float*)d_in[4];
    const float* W2   = (const float*)d_in[5];
    const float* b2   = (const float*)d_in[6];
    const float* Ws02 = (const float*)d_in[7];
    const float* bs02 = (const float*)d_in[8];
    const float* Ws13 = (const float*)d_in[9];
    const float* bs13 = (const float*)d_in[10];
    DanW d;
    d.Wd1 = (const float*)d_in[11];
    d.bd1 = (const float*)d_in[12];
    d.Wd2 = (const float*)d_in[13];
    d.bd2 = (const float*)d_in[14];
    d.Wd3 = (const float*)d_in[15];
    d.bd3 = (const float*)d_in[16];
    float* out = (float*)d_out;

    float* ws      = (float*)d_ws;
    float* a0      = ws;         // 4096
    float* a1      = ws + DD;    // 4096
    float* partial = ws + 2 * DD;

    // pick the largest row-split whose partial buffers fit in the workspace
    size_t avail_f = ws_size / sizeof(float);
    int rsplit = 1;
    const int cand[5] = {16, 8, 4, 2, 1};
    for (int c = 0; c < 5; ++c) {
        if ((size_t)2 * DD + (size_t)cand[c] * HSZ <= avail_f) { rsplit = cand[c]; break; }
    }
    int rps = DD / rsplit;

    k_layer0<<<DD / 64, 64, 0, stream>>>(x, W0, b0, a0, d);
    dim3 g2(HSZ4 / 256, rsplit);
    k_gemv<<<g2, 256, 0, stream>>>(a0, W1, partial, rps);
    k_danlayer1<<<DD / 64, 64, 0, stream>>>(partial, rsplit, b1, Ws02, bs02, x, a1, d);
    k_final<<<1, 256, 0, stream>>>(a0, a1, W2, b2, Ws13, bs13, out, d);
}